// Round 17
// baseline (124.016 us; speedup 1.0000x reference)
//
#include <hip/hip_runtime.h>

// Problem constants (fixed by setup_inputs: T=8, N=2048, D=256)
#define T_ALL 8
#define T1    7
#define NPTS  2048
#define DD    256
#define NPB   32                     // 64-col blocks per frame (wave tiles)
#define NGRP  1024                   // 16-row frag groups over all frames
#define MARGIN_THR 2.0e-4f           // 2x the 9.6e-5 rigorous (C-S) margin bound
#define RC_COLS 8                    // dst cols per recheck block
#define RC_ROWS 24                   // src rows staged per recheck batch

// ws layout (floats)
#define O_ND    0                                  // fp32 normalized [16384][256]
#define O_HI    (O_ND + T_ALL*NPTS*DD)             // bf16 hi, frag layout (shorts)
#define O_LO    (O_HI + T_ALL*NPTS*DD/2)
#define O_PV1   (O_LO + T_ALL*NPTS*DD/2)           // per (row, colblock) top1
#define O_PI1   (O_PV1 + T1*NPTS*NPB)
#define O_PV2   (O_PI1 + T1*NPTS*NPB)              // per (row, colblock) top2
#define O_BEST  (O_PV2 + T1*NPTS*NPB)              // u64 [14336]
#define O_WL    (O_BEST + T1*NPTS*2)               // int per-t worklists [7][2048]
#define O_CNT   (O_WL + T1*NPTS)                   // int cntT[8]

typedef __attribute__((ext_vector_type(8))) short short8v;   // 8 bf16 (4 VGPR)
typedef __attribute__((ext_vector_type(4))) float float4v;   // MFMA acc

__device__ __forceinline__ unsigned short f2bf(float x) {    // RNE f32->bf16
    unsigned u = __float_as_uint(x);
    return (unsigned short)((u + 0x7FFFu + ((u >> 16) & 1u)) >> 16);
}
__device__ __forceinline__ float bf2f(unsigned short h) {
    return __uint_as_float(((unsigned)h) << 16);
}
// monotone pack: larger value wins; equal value -> smaller idx wins
__device__ __forceinline__ unsigned long long packVI(float v, int idx) {
    unsigned int b = __float_as_uint(v);
    b = (b & 0x80000000u) ? ~b : (b | 0x80000000u);
    return ((unsigned long long)b << 32) | (unsigned int)(NPTS - 1 - idx);
}

// ---------------------------------------------------------------------------
// Kernel 1: normalize rows; emit fp32 nd + bf16 hi/lo in MFMA-frag layout.
// NEW tile order: tile(rd, group) at shorts offset (rd*NGRP + group)*512 —
// a round's 4 consecutive groups are CONTIGUOUS 1KB tiles, so match loads
// them from one base pointer + {0,1024,2048,3072}B immediate offsets (R16
// recomputed 16 fresh 64-bit addresses/round: VALUBusy 39% = issue-bound).
// Within a tile: lane=(row&15)+16*((k'>>2)&3), e=4*((k'>>4)&1)+(k'&3),
// k'=k-32*rd. A and B use the SAME map -> HW k-permutation cancels.
// ---------------------------------------------------------------------------
__global__ __launch_bounds__(256) void prep_kernel(const float* __restrict__ desc,
                                                   float* __restrict__ nd,
                                                   ushort* __restrict__ ghi,
                                                   ushort* __restrict__ glo,
                                                   int* __restrict__ cntT) {
    __shared__ ushort hiS[4096];                   // 8 KB: 8 ksteps x 512 shorts
    __shared__ ushort loS[4096];
    const int tid = threadIdx.x;
    const int grp = blockIdx.x;                    // 0..1023
    if (grp == 0 && tid < 8) cntT[tid] = 0;
    const int rl  = tid >> 4;                      // row in group
    const int kc  = tid & 15;                      // 16-float chunk
    const int row = grp * 16 + rl;

    const float* sp = desc + (size_t)row * DD + kc * 16;
    float4 v[4];
    float s = 0.f;
#pragma unroll
    for (int j = 0; j < 4; ++j) {
        v[j] = reinterpret_cast<const float4*>(sp)[j];
        s += v[j].x * v[j].x + v[j].y * v[j].y + v[j].z * v[j].z + v[j].w * v[j].w;
    }
#pragma unroll
    for (int m = 1; m <= 8; m <<= 1) s += __shfl_xor(s, m, 64);  // 16-lane row group
    float n = fmaxf(sqrtf(s), 1e-8f);

    float4 o[4];
    float* ndp = nd + (size_t)row * DD + kc * 16;
#pragma unroll
    for (int j = 0; j < 4; ++j) {
        o[j] = make_float4(v[j].x / n, v[j].y / n, v[j].z / n, v[j].w / n);
        reinterpret_cast<float4*>(ndp)[j] = o[j];
    }
    const int sbase = (kc >> 1) * 512 + rl * 8 + (kc & 1) * 4;   // shorts
#pragma unroll
    for (int g = 0; g < 4; ++g) {
        float xs[4] = {o[g].x, o[g].y, o[g].z, o[g].w};
        ushort4 h, l;
        h.x = f2bf(xs[0]); l.x = f2bf(xs[0] - bf2f(h.x));
        h.y = f2bf(xs[1]); l.y = f2bf(xs[1] - bf2f(h.y));
        h.z = f2bf(xs[2]); l.z = f2bf(xs[2] - bf2f(h.z));
        h.w = f2bf(xs[3]); l.w = f2bf(xs[3] - bf2f(h.w));
        *reinterpret_cast<ushort4*>(&hiS[sbase + g * 128]) = h;
        *reinterpret_cast<ushort4*>(&loS[sbase + g * 128]) = l;
    }
    __syncthreads();
    // copy-out: 8 tiles of 1KB per tensor, each at (rd*NGRP+grp)*1KB
    const int ch = tid >> 5;                       // rd 0..7
    const int cw = tid & 31;                       // 32 thr x 32B = 1KB
    const uint4* hs = reinterpret_cast<const uint4*>(hiS);
    const uint4* ls = reinterpret_cast<const uint4*>(loS);
    uint4* hd = reinterpret_cast<uint4*>(ghi + (((size_t)ch * NGRP + grp) << 9));
    uint4* ld = reinterpret_cast<uint4*>(glo + (((size_t)ch * NGRP + grp) << 9));
    hd[cw * 2 + 0] = hs[ch * 64 + cw * 2 + 0];
    hd[cw * 2 + 1] = hs[ch * 64 + cw * 2 + 1];
    ld[cw * 2 + 0] = ls[ch * 64 + cw * 2 + 0];
    ld[cw * 2 + 1] = ls[ch * 64 + cw * 2 + 1];
}

// ---------------------------------------------------------------------------
// Kernel 2: bf16 MFMA match, direct global->register fragments, register
// E/O double-buffering, RUNNING-POINTER addressing. One wave per 64x64 tile,
// no LDS, no barriers. Per round: 16 loads from 8 base pointers (A/B x hi/lo
// x E/O-shared) with immediate offsets; pointers advance by the rd-stride
// (NGRP*512 shorts) -- ~8 VALU/round vs R16's ~120 (VALUBusy 39% -> issue-
// bound). s_setprio(1) wraps the MFMA clusters (waves are phase-independent
// here, the regime where setprio pays). Fused hi/lo: hh+hl+lh into one
// accumulator. Bijective chunked XCD swizzle for L2 locality.
// ---------------------------------------------------------------------------
__global__ __launch_bounds__(64) void match_kernel(const ushort* __restrict__ ghi,
                                                   const ushort* __restrict__ glo,
                                                   float* __restrict__ pV1,
                                                   int* __restrict__ pI1,
                                                   float* __restrict__ pV2) {
    const int bid = blockIdx.x;                    // 7168 = 7 * 32 * 32
    const int swz = (bid & 7) * (7168 / 8) + (bid >> 3);   // bijective (7168%8==0)
    const int t   = swz >> 10;
    const int rb  = (swz >> 5) & 31;               // 64-row panel
    const int cb  = swz & 31;                      // 64-col panel
    const int l   = threadIdx.x;
    const size_t l8 = (size_t)(l << 3);            // lane's 8 shorts

    const int agrp = t * 128 + rb * 4;             // A frag groups (16 rows each)
    const int bgrp = (t + 1) * 128 + cb * 4;       // B frag groups
    const size_t RSTRIDE = (size_t)NGRP << 9;      // shorts per rd step

    const ushort* pAh = ghi + ((size_t)agrp << 9) + l8;
    const ushort* pAl = glo + ((size_t)agrp << 9) + l8;
    const ushort* pBh = ghi + ((size_t)bgrp << 9) + l8;
    const ushort* pBl = glo + ((size_t)bgrp << 9) + l8;

    float4v acc[4][4];
#pragma unroll
    for (int fa = 0; fa < 4; ++fa)
#pragma unroll
        for (int fb = 0; fb < 4; ++fb) acc[fa][fb] = (float4v){0.f, 0.f, 0.f, 0.f};

    short8v ahE[4], alE[4], bhE[4], blE[4];        // even-round fragment set
    short8v ahO[4], alO[4], bhO[4], blO[4];        // odd-round fragment set

    auto load = [&](short8v* ah, short8v* al, short8v* bh, short8v* bl) {
#pragma unroll
        for (int f = 0; f < 4; ++f) {              // f*1024B: immediate offsets
            ah[f] = *reinterpret_cast<const short8v*>(pAh + (f << 9));
            al[f] = *reinterpret_cast<const short8v*>(pAl + (f << 9));
            bh[f] = *reinterpret_cast<const short8v*>(pBh + (f << 9));
            bl[f] = *reinterpret_cast<const short8v*>(pBl + (f << 9));
        }
    };
    auto adv = [&]() { pAh += RSTRIDE; pAl += RSTRIDE; pBh += RSTRIDE; pBl += RSTRIDE; };
    auto compute = [&](const short8v* ah, const short8v* al,
                       const short8v* bh, const short8v* bl) {
        __builtin_amdgcn_s_setprio(1);
#pragma unroll
        for (int fa = 0; fa < 4; ++fa) {
#pragma unroll
            for (int fb = 0; fb < 4; ++fb)
                acc[fa][fb] = __builtin_amdgcn_mfma_f32_16x16x32_bf16(ah[fa], bh[fb], acc[fa][fb], 0, 0, 0);
#pragma unroll
            for (int fb = 0; fb < 4; ++fb)
                acc[fa][fb] = __builtin_amdgcn_mfma_f32_16x16x32_bf16(ah[fa], bl[fb], acc[fa][fb], 0, 0, 0);
#pragma unroll
            for (int fb = 0; fb < 4; ++fb)
                acc[fa][fb] = __builtin_amdgcn_mfma_f32_16x16x32_bf16(al[fa], bh[fb], acc[fa][fb], 0, 0, 0);
        }
        __builtin_amdgcn_s_setprio(0);
    };

    load(ahE, alE, bhE, blE);                      // rd 0
    adv();                                         // -> rd 1
#pragma unroll 1
    for (int rd = 0; rd < 8; rd += 2) {
        load(ahO, alO, bhO, blO);                  // rd+1; flies under E-compute
        adv();                                     // -> rd+2
        compute(ahE, alE, bhE, blE);
        if (rd + 2 < 8) {
            load(ahE, alE, bhE, blE);              // rd+2; flies under O-compute
            adv();
        }
        compute(ahO, alO, bhO, blO);
    }

    // ---- epilogue (in-wave): D row = fa*16+4*(l>>4)+r, col = cb*64+fb*16+(l&15)
#pragma unroll
    for (int fa = 0; fa < 4; ++fa) {
#pragma unroll
        for (int r = 0; r < 4; ++r) {
            float v1 = -3.0e38f, v2 = -3.0e38f; int i1 = 0;
#pragma unroll
            for (int fb = 0; fb < 4; ++fb) {
                float x  = acc[fa][fb][r];
                int  col = cb * 64 + fb * 16 + (l & 15);
                if (x > v1) { v2 = v1; v1 = x; i1 = col; }
                else        { v2 = fmaxf(v2, x); }
            }
#pragma unroll
            for (int m = 1; m <= 8; m <<= 1) {     // 16-lane butterfly
                float ov1 = __shfl_xor(v1, m);
                int   oi1 = __shfl_xor(i1, m);
                float ov2 = __shfl_xor(v2, m);
                bool take = (ov1 > v1) || (ov1 == v1 && oi1 < i1);
                float nv2 = take ? fmaxf(ov2, v1) : fmaxf(v2, ov1);
                v1 = take ? ov1 : v1;  i1 = take ? oi1 : i1;  v2 = nv2;
            }
            if ((l & 15) == 0) {
                int grow = t * NPTS + rb * 64 + fa * 16 + (l >> 4) * 4 + r;
                int idx  = grow * NPB + cb;
                pV1[idx] = v1; pI1[idx] = i1; pV2[idx] = v2;
            }
        }
    }
}

// ---------------------------------------------------------------------------
// Kernel 3: global top-2 margin per row; near-ties -> per-t worklist; safe
// rows commit approx best (value error <= 4.8e-5 << bf16-granular bar).
// ---------------------------------------------------------------------------
__global__ __launch_bounds__(256) void margin_kernel(const float* __restrict__ pV1,
                                                     const int* __restrict__ pI1,
                                                     const float* __restrict__ pV2,
                                                     unsigned long long* __restrict__ best,
                                                     int* __restrict__ wlT,
                                                     int* __restrict__ cntT) {
    int r = blockIdx.x * 256 + threadIdx.x;        // 0..14335
    int t = r >> 11;
    float v1 = -3.0e38f, v2 = -3.0e38f; int i1 = 0;
#pragma unroll
    for (int cbk = 0; cbk < NPB; ++cbk) {          // ascending -> first-occurrence
        int idx = r * NPB + cbk;
        float a1 = pV1[idx]; int ai = pI1[idx]; float a2 = pV2[idx];
        if (a1 > v1) { v2 = fmaxf(v1, a2); v1 = a1; i1 = ai; }
        else         { v2 = fmaxf(v2, a1); }
    }
    if (v1 - v2 < MARGIN_THR) {
        best[r] = 0ull;
        int slot = atomicAdd(&cntT[t], 1);
        wlT[t * NPTS + slot] = r & (NPTS - 1);     // row within frame
    } else {
        best[r] = packVI(v1, i1);
    }
}

// ---------------------------------------------------------------------------
// Kernel 4: exact fp32 rescore, loop-inverted + wave-parallel rows.
// Block = (t, 8-col slab); batch-stage <=24 flagged src rows + the dst slab
// in conflict-free [*][8][33] layouts; wave w handles rows w, w+4, ...
// independently; one atomicMax per row per slab (order-independent).
// ---------------------------------------------------------------------------
__global__ __launch_bounds__(256) void recheck_kernel(const float* __restrict__ nd,
                                                      const int* __restrict__ wlT,
                                                      const int* __restrict__ cntT,
                                                      unsigned long long* __restrict__ best) {
    __shared__ float dstS[RC_COLS][8][33];         // 8.25 KB  [col][kseg][k]
    __shared__ float srcS[RC_ROWS][8][33];         // 24.75 KB [row][kseg][k]
    const int t   = blockIdx.x >> 8;               // grid = 7 * 256
    const int cc  = blockIdx.x & 255;
    const int nr  = cntT[t];
    if (nr == 0) return;
    const int tid  = threadIdx.x;
    const int w    = tid >> 6;
    const int l    = tid & 63;
    const int col0 = cc * RC_COLS;

    {   // stage 8 dst cols: thread col=tid>>5, 2 float4 (8 floats) each
        const int col = tid >> 5;
        const int k8  = tid & 31;
        const float* dp = nd + ((size_t)((t + 1) * NPTS) + col0 + col) * DD;
#pragma unroll
        for (int j = 0; j < 2; ++j) {
            float4 v = reinterpret_cast<const float4*>(dp)[k8 * 2 + j];
            int k = (k8 * 2 + j) * 4;
            dstS[col][k >> 5][k & 31]       = v.x;
            dstS[col][(k+1) >> 5][(k+1)&31] = v.y;
            dstS[col][(k+2) >> 5][(k+2)&31] = v.z;
            dstS[col][(k+3) >> 5][(k+3)&31] = v.w;
        }
    }

#pragma unroll 1
    for (int base = 0; base < nr; base += RC_ROWS) {
        const int nb = min(RC_ROWS, nr - base);
        __syncthreads();                           // srcS free (dstS ready, 1st)
        for (int idx = tid; idx < nb * 64; idx += 256) {
            const int ri = idx >> 6, ln = idx & 63;
            const int row = wlT[t * NPTS + base + ri];
            float4 v = reinterpret_cast<const float4*>(
                nd + ((size_t)(t * NPTS) + row) * DD)[ln];
            int k = ln * 4;
            srcS[ri][k >> 5][k & 31]       = v.x;
            srcS[ri][(k+1) >> 5][(k+1)&31] = v.y;
            srcS[ri][(k+2) >> 5][(k+2)&31] = v.z;
            srcS[ri][(k+3) >> 5][(k+3)&31] = v.w;
        }
        __syncthreads();                           // batch staged

        const int colx = l & 7, ks = l >> 3;
#pragma unroll 1
        for (int ri = w; ri < nb; ri += 4) {       // waves independent
            const int row = wlT[t * NPTS + base + ri];
            const int r   = t * NPTS + row;
            float p = 0.f;
#pragma unroll
            for (int k = 0; k < 32; ++k)
                p = fmaf(srcS[ri][ks][k], dstS[colx][ks][k], p);
            p += __shfl_xor(p, 8); p += __shfl_xor(p, 16); p += __shfl_xor(p, 32);
            float bv = p; int bi = col0 + colx;
#pragma unroll
            for (int m = 1; m <= 4; m <<= 1) {     // top-1 across 8 cols
                float ov = __shfl_xor(bv, m);
                int   oi = __shfl_xor(bi, m);
                if (ov > bv || (ov == bv && oi < bi)) { bv = ov; bi = oi; }
            }
            if (l == 0) atomicMax(&best[r], packVI(bv, bi));
        }
    }
}

// ---------------------------------------------------------------------------
// Kernel 5: unpack best[], gather matched points, write outputs.
// ---------------------------------------------------------------------------
__global__ __launch_bounds__(256) void final_kernel(const unsigned long long* __restrict__ best,
                                                    const float* __restrict__ pts,
                                                    float* __restrict__ out) {
    int r = blockIdx.x * 256 + threadIdx.x;
    int t = r >> 11;
    unsigned long long p = best[r];
    int idx = NPTS - 1 - (int)(p & 0xFFFFFFFFull);
    unsigned int b = (unsigned int)(p >> 32);
    b = (b & 0x80000000u) ? (b & 0x7FFFFFFFu) : ~b;
    out[(size_t)T1 * NPTS * 2 + r] = __uint_as_float(b);
    const float* q = pts + ((size_t)((t + 1) * NPTS) + idx) * 2;
    out[(size_t)r * 2 + 0] = q[0];
    out[(size_t)r * 2 + 1] = q[1];
}

// ---------------------------------------------------------------------------
extern "C" void kernel_launch(void* const* d_in, const int* in_sizes, int n_in,
                              void* d_out, int out_size, void* d_ws, size_t ws_size,
                              hipStream_t stream) {
    const float* desc = (const float*)d_in[0];     // [8, 2048, 256] fp32
    const float* pts  = (const float*)d_in[1];     // [8, 2048, 2]   fp32
    float* ws = (float*)d_ws;
    float* nd  = ws + O_ND;
    ushort* ghi = (ushort*)(ws + O_HI);
    ushort* glo = (ushort*)(ws + O_LO);
    float* pV1 = ws + O_PV1;
    int*   pI1 = (int*)(ws + O_PI1);
    float* pV2 = ws + O_PV2;
    unsigned long long* best = (unsigned long long*)(ws + O_BEST);
    int* wlT  = (int*)(ws + O_WL);
    int* cntT = (int*)(ws + O_CNT);

    prep_kernel<<<T_ALL * NPTS / 16, 256, 0, stream>>>(desc, nd, ghi, glo, cntT);
    match_kernel<<<T1 * 32 * 32, 64, 0, stream>>>(ghi, glo, pV1, pI1, pV2);
    margin_kernel<<<(T1 * NPTS) / 256, 256, 0, stream>>>(pV1, pI1, pV2, best, wlT, cntT);
    recheck_kernel<<<T1 * 256, 256, 0, stream>>>(nd, wlT, cntT, best);
    final_kernel<<<(T1 * NPTS) / 256, 256, 0, stream>>>(best, pts, (float*)d_out);
}

// Round 18
// 112.232 us; speedup vs baseline: 1.1050x; 1.1050x over previous
//
#include <hip/hip_runtime.h>

// Problem constants (fixed by setup_inputs: T=8, N=2048, D=256)
#define T_ALL 8
#define T1    7
#define NPTS  2048
#define DD    256
#define NPB   32                     // 64-col blocks per frame (wave tiles)
#define NGRP  1024                   // 16-row frag groups over all frames
#define MARGIN_THR 2.0e-4f           // 2x the 9.6e-5 rigorous (C-S) margin bound
#define RC_COLS 8                    // dst cols per recheck block
#define RC_ROWS 24                   // src rows staged per recheck batch

// ws layout (floats)
#define O_ND    0                                  // fp32 normalized [16384][256]
#define O_HI    (O_ND + T_ALL*NPTS*DD)             // bf16 hi, frag layout (shorts)
#define O_LO    (O_HI + T_ALL*NPTS*DD/2)
#define O_PV1   (O_LO + T_ALL*NPTS*DD/2)           // per (row, colblock) top1
#define O_PI1   (O_PV1 + T1*NPTS*NPB)
#define O_PV2   (O_PI1 + T1*NPTS*NPB)              // per (row, colblock) top2
#define O_BEST  (O_PV2 + T1*NPTS*NPB)              // u64 [14336]
#define O_WL    (O_BEST + T1*NPTS*2)               // int per-t worklists [7][2048]
#define O_CNT   (O_WL + T1*NPTS)                   // int cntT[8]

typedef __attribute__((ext_vector_type(8))) short short8v;   // 8 bf16 (4 VGPR)
typedef __attribute__((ext_vector_type(4))) float float4v;   // MFMA acc

__device__ __forceinline__ unsigned short f2bf(float x) {    // RNE f32->bf16
    unsigned u = __float_as_uint(x);
    return (unsigned short)((u + 0x7FFFu + ((u >> 16) & 1u)) >> 16);
}
__device__ __forceinline__ float bf2f(unsigned short h) {
    return __uint_as_float(((unsigned)h) << 16);
}
// monotone pack: larger value wins; equal value -> smaller idx wins
__device__ __forceinline__ unsigned long long packVI(float v, int idx) {
    unsigned int b = __float_as_uint(v);
    b = (b & 0x80000000u) ? ~b : (b | 0x80000000u);
    return ((unsigned long long)b << 32) | (unsigned int)(NPTS - 1 - idx);
}

// ---------------------------------------------------------------------------
// Kernel 1: normalize rows; emit fp32 nd + bf16 hi/lo in MFMA-frag layout.
// Tile order [rd][group]: tile(rd, group) at shorts offset (rd*NGRP+grp)*512;
// a round's 4 consecutive groups are CONTIGUOUS 1KB tiles -> match loads via
// one base pointer + {0,1024,2048,3072}B immediate offsets. Within a tile:
// lane=(row&15)+16*((k'>>2)&3), e=4*((k'>>4)&1)+(k'&3), k'=k-32*rd. A and B
// use the SAME map -> HW k-permutation cancels in the dot product.
// ---------------------------------------------------------------------------
__global__ __launch_bounds__(256) void prep_kernel(const float* __restrict__ desc,
                                                   float* __restrict__ nd,
                                                   ushort* __restrict__ ghi,
                                                   ushort* __restrict__ glo,
                                                   int* __restrict__ cntT) {
    __shared__ ushort hiS[4096];                   // 8 KB: 8 ksteps x 512 shorts
    __shared__ ushort loS[4096];
    const int tid = threadIdx.x;
    const int grp = blockIdx.x;                    // 0..1023
    if (grp == 0 && tid < 8) cntT[tid] = 0;
    const int rl  = tid >> 4;                      // row in group
    const int kc  = tid & 15;                      // 16-float chunk
    const int row = grp * 16 + rl;

    const float* sp = desc + (size_t)row * DD + kc * 16;
    float4 v[4];
    float s = 0.f;
#pragma unroll
    for (int j = 0; j < 4; ++j) {
        v[j] = reinterpret_cast<const float4*>(sp)[j];
        s += v[j].x * v[j].x + v[j].y * v[j].y + v[j].z * v[j].z + v[j].w * v[j].w;
    }
#pragma unroll
    for (int m = 1; m <= 8; m <<= 1) s += __shfl_xor(s, m, 64);  // 16-lane row group
    float n = fmaxf(sqrtf(s), 1e-8f);

    float4 o[4];
    float* ndp = nd + (size_t)row * DD + kc * 16;
#pragma unroll
    for (int j = 0; j < 4; ++j) {
        o[j] = make_float4(v[j].x / n, v[j].y / n, v[j].z / n, v[j].w / n);
        reinterpret_cast<float4*>(ndp)[j] = o[j];
    }
    const int sbase = (kc >> 1) * 512 + rl * 8 + (kc & 1) * 4;   // shorts
#pragma unroll
    for (int g = 0; g < 4; ++g) {
        float xs[4] = {o[g].x, o[g].y, o[g].z, o[g].w};
        ushort4 h, l;
        h.x = f2bf(xs[0]); l.x = f2bf(xs[0] - bf2f(h.x));
        h.y = f2bf(xs[1]); l.y = f2bf(xs[1] - bf2f(h.y));
        h.z = f2bf(xs[2]); l.z = f2bf(xs[2] - bf2f(h.z));
        h.w = f2bf(xs[3]); l.w = f2bf(xs[3] - bf2f(h.w));
        *reinterpret_cast<ushort4*>(&hiS[sbase + g * 128]) = h;
        *reinterpret_cast<ushort4*>(&loS[sbase + g * 128]) = l;
    }
    __syncthreads();
    // copy-out: 8 tiles of 1KB per tensor, each at (rd*NGRP+grp)*1KB
    const int ch = tid >> 5;                       // rd 0..7
    const int cw = tid & 31;                       // 32 thr x 32B = 1KB
    const uint4* hs = reinterpret_cast<const uint4*>(hiS);
    const uint4* ls = reinterpret_cast<const uint4*>(loS);
    uint4* hd = reinterpret_cast<uint4*>(ghi + (((size_t)ch * NGRP + grp) << 9));
    uint4* ld = reinterpret_cast<uint4*>(glo + (((size_t)ch * NGRP + grp) << 9));
    hd[cw * 2 + 0] = hs[ch * 64 + cw * 2 + 0];
    hd[cw * 2 + 1] = hs[ch * 64 + cw * 2 + 1];
    ld[cw * 2 + 0] = ls[ch * 64 + cw * 2 + 0];
    ld[cw * 2 + 1] = ls[ch * 64 + cw * 2 + 1];
}

// ---------------------------------------------------------------------------
// Kernel 2: bf16 MFMA match, direct global->register, FRAGMENT TIME-SHARING
// to fit the 128-reg granule (m69: waves/SIMD steps at <=64/128/256 unified
// regs; R15-R17's ~176 regs were hard-capped at 2 waves/SIMD -> one exposed
// memory latency per round couldn't be hidden; 70us vs 22us MFMA floor).
// Per round: load {bh,ah} -> pass hh -> load al -> pass lh (al*bh) ->
// OVERWRITE b<-bl -> pass hl (ah*bl). Live: 48 frag + 64 acc + ~12 addr
// <= 128 -> 4 waves/SIMD; TLP hides latency (m114 cross-wave overlap).
// __launch_bounds__(64,4) pins the allocator to the 128 budget.
// Bijective chunked XCD swizzle for L2 locality.
// ---------------------------------------------------------------------------
__global__ __launch_bounds__(64, 4) void match_kernel(const ushort* __restrict__ ghi,
                                                      const ushort* __restrict__ glo,
                                                      float* __restrict__ pV1,
                                                      int* __restrict__ pI1,
                                                      float* __restrict__ pV2) {
    const int bid = blockIdx.x;                    // 7168 = 7 * 32 * 32
    const int swz = (bid & 7) * (7168 / 8) + (bid >> 3);   // bijective (7168%8==0)
    const int t   = swz >> 10;
    const int rb  = (swz >> 5) & 31;               // 64-row panel
    const int cb  = swz & 31;                      // 64-col panel
    const int l   = threadIdx.x;
    const size_t l8 = (size_t)(l << 3);            // lane's 8 shorts

    const int agrp = t * 128 + rb * 4;             // A frag groups (16 rows each)
    const int bgrp = (t + 1) * 128 + cb * 4;       // B frag groups
    const size_t RSTRIDE = (size_t)NGRP << 9;      // shorts per rd step

    const ushort* pAh = ghi + ((size_t)agrp << 9) + l8;
    const ushort* pAl = glo + ((size_t)agrp << 9) + l8;
    const ushort* pBh = ghi + ((size_t)bgrp << 9) + l8;
    const ushort* pBl = glo + ((size_t)bgrp << 9) + l8;

    float4v acc[4][4];
#pragma unroll
    for (int fa = 0; fa < 4; ++fa)
#pragma unroll
        for (int fb = 0; fb < 4; ++fb) acc[fa][fb] = (float4v){0.f, 0.f, 0.f, 0.f};

    short8v ah[4], al[4], b[4];                    // b time-shares bh then bl

#pragma unroll 1
    for (int rd = 0; rd < 8; ++rd) {
#pragma unroll
        for (int f = 0; f < 4; ++f)                // f*1024B: immediate offsets
            b[f]  = *reinterpret_cast<const short8v*>(pBh + (f << 9));
#pragma unroll
        for (int f = 0; f < 4; ++f)
            ah[f] = *reinterpret_cast<const short8v*>(pAh + (f << 9));
        // pass hh: ah x bh
#pragma unroll
        for (int fa = 0; fa < 4; ++fa)
#pragma unroll
            for (int fb = 0; fb < 4; ++fb)
                acc[fa][fb] = __builtin_amdgcn_mfma_f32_16x16x32_bf16(ah[fa], b[fb], acc[fa][fb], 0, 0, 0);
#pragma unroll
        for (int f = 0; f < 4; ++f)
            al[f] = *reinterpret_cast<const short8v*>(pAl + (f << 9));
        // pass lh: al x bh
#pragma unroll
        for (int fa = 0; fa < 4; ++fa)
#pragma unroll
            for (int fb = 0; fb < 4; ++fb)
                acc[fa][fb] = __builtin_amdgcn_mfma_f32_16x16x32_bf16(al[fa], b[fb], acc[fa][fb], 0, 0, 0);
        // reuse b for bl
#pragma unroll
        for (int f = 0; f < 4; ++f)
            b[f]  = *reinterpret_cast<const short8v*>(pBl + (f << 9));
        // pass hl: ah x bl
#pragma unroll
        for (int fa = 0; fa < 4; ++fa)
#pragma unroll
            for (int fb = 0; fb < 4; ++fb)
                acc[fa][fb] = __builtin_amdgcn_mfma_f32_16x16x32_bf16(ah[fa], b[fb], acc[fa][fb], 0, 0, 0);
        pAh += RSTRIDE; pAl += RSTRIDE; pBh += RSTRIDE; pBl += RSTRIDE;
    }

    // ---- epilogue (in-wave): D row = fa*16+4*(l>>4)+r, col = cb*64+fb*16+(l&15)
#pragma unroll
    for (int fa = 0; fa < 4; ++fa) {
#pragma unroll
        for (int r = 0; r < 4; ++r) {
            float v1 = -3.0e38f, v2 = -3.0e38f; int i1 = 0;
#pragma unroll
            for (int fb = 0; fb < 4; ++fb) {
                float x  = acc[fa][fb][r];
                int  col = cb * 64 + fb * 16 + (l & 15);
                if (x > v1) { v2 = v1; v1 = x; i1 = col; }
                else        { v2 = fmaxf(v2, x); }
            }
#pragma unroll
            for (int m = 1; m <= 8; m <<= 1) {     // 16-lane butterfly
                float ov1 = __shfl_xor(v1, m);
                int   oi1 = __shfl_xor(i1, m);
                float ov2 = __shfl_xor(v2, m);
                bool take = (ov1 > v1) || (ov1 == v1 && oi1 < i1);
                float nv2 = take ? fmaxf(ov2, v1) : fmaxf(v2, ov1);
                v1 = take ? ov1 : v1;  i1 = take ? oi1 : i1;  v2 = nv2;
            }
            if ((l & 15) == 0) {
                int grow = t * NPTS + rb * 64 + fa * 16 + (l >> 4) * 4 + r;
                int idx  = grow * NPB + cb;
                pV1[idx] = v1; pI1[idx] = i1; pV2[idx] = v2;
            }
        }
    }
}

// ---------------------------------------------------------------------------
// Kernel 3: global top-2 margin per row; near-ties -> per-t worklist; safe
// rows commit approx best (value error <= 4.8e-5 << bf16-granular bar).
// ---------------------------------------------------------------------------
__global__ __launch_bounds__(256) void margin_kernel(const float* __restrict__ pV1,
                                                     const int* __restrict__ pI1,
                                                     const float* __restrict__ pV2,
                                                     unsigned long long* __restrict__ best,
                                                     int* __restrict__ wlT,
                                                     int* __restrict__ cntT) {
    int r = blockIdx.x * 256 + threadIdx.x;        // 0..14335
    int t = r >> 11;
    float v1 = -3.0e38f, v2 = -3.0e38f; int i1 = 0;
#pragma unroll
    for (int cbk = 0; cbk < NPB; ++cbk) {          // ascending -> first-occurrence
        int idx = r * NPB + cbk;
        float a1 = pV1[idx]; int ai = pI1[idx]; float a2 = pV2[idx];
        if (a1 > v1) { v2 = fmaxf(v1, a2); v1 = a1; i1 = ai; }
        else         { v2 = fmaxf(v2, a1); }
    }
    if (v1 - v2 < MARGIN_THR) {
        best[r] = 0ull;
        int slot = atomicAdd(&cntT[t], 1);
        wlT[t * NPTS + slot] = r & (NPTS - 1);     // row within frame
    } else {
        best[r] = packVI(v1, i1);
    }
}

// ---------------------------------------------------------------------------
// Kernel 4: exact fp32 rescore, loop-inverted + wave-parallel rows.
// Block = (t, 8-col slab); batch-stage <=24 flagged src rows + the dst slab
// in conflict-free [*][8][33] layouts; wave w handles rows w, w+4, ...
// independently; one atomicMax per row per slab (order-independent).
// ---------------------------------------------------------------------------
__global__ __launch_bounds__(256) void recheck_kernel(const float* __restrict__ nd,
                                                      const int* __restrict__ wlT,
                                                      const int* __restrict__ cntT,
                                                      unsigned long long* __restrict__ best) {
    __shared__ float dstS[RC_COLS][8][33];         // 8.25 KB  [col][kseg][k]
    __shared__ float srcS[RC_ROWS][8][33];         // 24.75 KB [row][kseg][k]
    const int t   = blockIdx.x >> 8;               // grid = 7 * 256
    const int cc  = blockIdx.x & 255;
    const int nr  = cntT[t];
    if (nr == 0) return;
    const int tid  = threadIdx.x;
    const int w    = tid >> 6;
    const int l    = tid & 63;
    const int col0 = cc * RC_COLS;

    {   // stage 8 dst cols: thread col=tid>>5, 2 float4 (8 floats) each
        const int col = tid >> 5;
        const int k8  = tid & 31;
        const float* dp = nd + ((size_t)((t + 1) * NPTS) + col0 + col) * DD;
#pragma unroll
        for (int j = 0; j < 2; ++j) {
            float4 v = reinterpret_cast<const float4*>(dp)[k8 * 2 + j];
            int k = (k8 * 2 + j) * 4;
            dstS[col][k >> 5][k & 31]       = v.x;
            dstS[col][(k+1) >> 5][(k+1)&31] = v.y;
            dstS[col][(k+2) >> 5][(k+2)&31] = v.z;
            dstS[col][(k+3) >> 5][(k+3)&31] = v.w;
        }
    }

#pragma unroll 1
    for (int base = 0; base < nr; base += RC_ROWS) {
        const int nb = min(RC_ROWS, nr - base);
        __syncthreads();                           // srcS free (dstS ready, 1st)
        for (int idx = tid; idx < nb * 64; idx += 256) {
            const int ri = idx >> 6, ln = idx & 63;
            const int row = wlT[t * NPTS + base + ri];
            float4 v = reinterpret_cast<const float4*>(
                nd + ((size_t)(t * NPTS) + row) * DD)[ln];
            int k = ln * 4;
            srcS[ri][k >> 5][k & 31]       = v.x;
            srcS[ri][(k+1) >> 5][(k+1)&31] = v.y;
            srcS[ri][(k+2) >> 5][(k+2)&31] = v.z;
            srcS[ri][(k+3) >> 5][(k+3)&31] = v.w;
        }
        __syncthreads();                           // batch staged

        const int colx = l & 7, ks = l >> 3;
#pragma unroll 1
        for (int ri = w; ri < nb; ri += 4) {       // waves independent
            const int row = wlT[t * NPTS + base + ri];
            const int r   = t * NPTS + row;
            float p = 0.f;
#pragma unroll
            for (int k = 0; k < 32; ++k)
                p = fmaf(srcS[ri][ks][k], dstS[colx][ks][k], p);
            p += __shfl_xor(p, 8); p += __shfl_xor(p, 16); p += __shfl_xor(p, 32);
            float bv = p; int bi = col0 + colx;
#pragma unroll
            for (int m = 1; m <= 4; m <<= 1) {     // top-1 across 8 cols
                float ov = __shfl_xor(bv, m);
                int   oi = __shfl_xor(bi, m);
                if (ov > bv || (ov == bv && oi < bi)) { bv = ov; bi = oi; }
            }
            if (l == 0) atomicMax(&best[r], packVI(bv, bi));
        }
    }
}

// ---------------------------------------------------------------------------
// Kernel 5: unpack best[], gather matched points, write outputs.
// ---------------------------------------------------------------------------
__global__ __launch_bounds__(256) void final_kernel(const unsigned long long* __restrict__ best,
                                                    const float* __restrict__ pts,
                                                    float* __restrict__ out) {
    int r = blockIdx.x * 256 + threadIdx.x;
    int t = r >> 11;
    unsigned long long p = best[r];
    int idx = NPTS - 1 - (int)(p & 0xFFFFFFFFull);
    unsigned int b = (unsigned int)(p >> 32);
    b = (b & 0x80000000u) ? (b & 0x7FFFFFFFu) : ~b;
    out[(size_t)T1 * NPTS * 2 + r] = __uint_as_float(b);
    const float* q = pts + ((size_t)((t + 1) * NPTS) + idx) * 2;
    out[(size_t)r * 2 + 0] = q[0];
    out[(size_t)r * 2 + 1] = q[1];
}

// ---------------------------------------------------------------------------
extern "C" void kernel_launch(void* const* d_in, const int* in_sizes, int n_in,
                              void* d_out, int out_size, void* d_ws, size_t ws_size,
                              hipStream_t stream) {
    const float* desc = (const float*)d_in[0];     // [8, 2048, 256] fp32
    const float* pts  = (const float*)d_in[1];     // [8, 2048, 2]   fp32
    float* ws = (float*)d_ws;
    float* nd  = ws + O_ND;
    ushort* ghi = (ushort*)(ws + O_HI);
    ushort* glo = (ushort*)(ws + O_LO);
    float* pV1 = ws + O_PV1;
    int*   pI1 = (int*)(ws + O_PI1);
    float* pV2 = ws + O_PV2;
    unsigned long long* best = (unsigned long long*)(ws + O_BEST);
    int* wlT  = (int*)(ws + O_WL);
    int* cntT = (int*)(ws + O_CNT);

    prep_kernel<<<T_ALL * NPTS / 16, 256, 0, stream>>>(desc, nd, ghi, glo, cntT);
    match_kernel<<<T1 * 32 * 32, 64, 0, stream>>>(ghi, glo, pV1, pI1, pV2);
    margin_kernel<<<(T1 * NPTS) / 256, 256, 0, stream>>>(pV1, pI1, pV2, best, wlT, cntT);
    recheck_kernel<<<T1 * 256, 256, 0, stream>>>(nd, wlT, cntT, best);
    final_kernel<<<(T1 * NPTS) / 256, 256, 0, stream>>>(best, pts, (float*)d_out);
}

// Round 19
// 111.802 us; speedup vs baseline: 1.1092x; 1.0039x over previous
//
#include <hip/hip_runtime.h>

// Problem constants (fixed by setup_inputs: T=8, N=2048, D=256)
#define T_ALL 8
#define T1    7
#define NPTS  2048
#define DD    256
#define NPB   32                     // 64-col blocks per frame (wave tiles)
#define NGRP  1024                   // 16-row frag groups over all frames
#define MARGIN_THR 2.0e-4f           // 2x the 9.6e-5 rigorous (C-S) margin bound
#define RC_COLS 8                    // dst cols per recheck block
#define RC_ROWS 24                   // src rows staged per recheck batch

// ws layout (floats)
#define O_ND    0                                  // fp32 normalized [16384][256]
#define O_HI    (O_ND + T_ALL*NPTS*DD)             // bf16 hi, frag layout (shorts)
#define O_LO    (O_HI + T_ALL*NPTS*DD/2)
#define O_PV1   (O_LO + T_ALL*NPTS*DD/2)           // per (row, colblock) top1
#define O_PI1   (O_PV1 + T1*NPTS*NPB)
#define O_PV2   (O_PI1 + T1*NPTS*NPB)              // per (row, colblock) top2
#define O_BEST  (O_PV2 + T1*NPTS*NPB)              // u64 [14336]
#define O_WL    (O_BEST + T1*NPTS*2)               // int per-t worklists [7][2048]
#define O_CNT   (O_WL + T1*NPTS)                   // int cntT[8]

typedef __attribute__((ext_vector_type(8))) short short8v;   // 8 bf16 (4 VGPR)
typedef __attribute__((ext_vector_type(4))) float float4v;   // MFMA acc

__device__ __forceinline__ unsigned short f2bf(float x) {    // RNE f32->bf16
    unsigned u = __float_as_uint(x);
    return (unsigned short)((u + 0x7FFFu + ((u >> 16) & 1u)) >> 16);
}
__device__ __forceinline__ float bf2f(unsigned short h) {
    return __uint_as_float(((unsigned)h) << 16);
}
// monotone pack: larger value wins; equal value -> smaller idx wins
__device__ __forceinline__ unsigned long long packVI(float v, int idx) {
    unsigned int b = __float_as_uint(v);
    b = (b & 0x80000000u) ? ~b : (b | 0x80000000u);
    return ((unsigned long long)b << 32) | (unsigned int)(NPTS - 1 - idx);
}

// ---------------------------------------------------------------------------
// Kernel 1: normalize rows; emit fp32 nd + bf16 hi/lo in MFMA-frag layout.
// Tile order [rd][group]: tile(rd, group) at shorts offset (rd*NGRP+grp)*512;
// a round's 4 consecutive groups are CONTIGUOUS 1KB tiles -> match loads via
// one base pointer + {0,1024,2048,3072}B immediate offsets. Within a tile:
// lane=(row&15)+16*((k'>>2)&3), e=4*((k'>>4)&1)+(k'&3), k'=k-32*rd. A and B
// use the SAME map -> HW k-permutation cancels in the dot product.
// ---------------------------------------------------------------------------
__global__ __launch_bounds__(256) void prep_kernel(const float* __restrict__ desc,
                                                   float* __restrict__ nd,
                                                   ushort* __restrict__ ghi,
                                                   ushort* __restrict__ glo,
                                                   int* __restrict__ cntT) {
    __shared__ ushort hiS[4096];                   // 8 KB: 8 ksteps x 512 shorts
    __shared__ ushort loS[4096];
    const int tid = threadIdx.x;
    const int grp = blockIdx.x;                    // 0..1023
    if (grp == 0 && tid < 8) cntT[tid] = 0;
    const int rl  = tid >> 4;                      // row in group
    const int kc  = tid & 15;                      // 16-float chunk
    const int row = grp * 16 + rl;

    const float* sp = desc + (size_t)row * DD + kc * 16;
    float4 v[4];
    float s = 0.f;
#pragma unroll
    for (int j = 0; j < 4; ++j) {
        v[j] = reinterpret_cast<const float4*>(sp)[j];
        s += v[j].x * v[j].x + v[j].y * v[j].y + v[j].z * v[j].z + v[j].w * v[j].w;
    }
#pragma unroll
    for (int m = 1; m <= 8; m <<= 1) s += __shfl_xor(s, m, 64);  // 16-lane row group
    float n = fmaxf(sqrtf(s), 1e-8f);

    float4 o[4];
    float* ndp = nd + (size_t)row * DD + kc * 16;
#pragma unroll
    for (int j = 0; j < 4; ++j) {
        o[j] = make_float4(v[j].x / n, v[j].y / n, v[j].z / n, v[j].w / n);
        reinterpret_cast<float4*>(ndp)[j] = o[j];
    }
    const int sbase = (kc >> 1) * 512 + rl * 8 + (kc & 1) * 4;   // shorts
#pragma unroll
    for (int g = 0; g < 4; ++g) {
        float xs[4] = {o[g].x, o[g].y, o[g].z, o[g].w};
        ushort4 h, l;
        h.x = f2bf(xs[0]); l.x = f2bf(xs[0] - bf2f(h.x));
        h.y = f2bf(xs[1]); l.y = f2bf(xs[1] - bf2f(h.y));
        h.z = f2bf(xs[2]); l.z = f2bf(xs[2] - bf2f(h.z));
        h.w = f2bf(xs[3]); l.w = f2bf(xs[3] - bf2f(h.w));
        *reinterpret_cast<ushort4*>(&hiS[sbase + g * 128]) = h;
        *reinterpret_cast<ushort4*>(&loS[sbase + g * 128]) = l;
    }
    __syncthreads();
    // copy-out: 8 tiles of 1KB per tensor, each at (rd*NGRP+grp)*1KB
    const int ch = tid >> 5;                       // rd 0..7
    const int cw = tid & 31;                       // 32 thr x 32B = 1KB
    const uint4* hs = reinterpret_cast<const uint4*>(hiS);
    const uint4* ls = reinterpret_cast<const uint4*>(loS);
    uint4* hd = reinterpret_cast<uint4*>(ghi + (((size_t)ch * NGRP + grp) << 9));
    uint4* ld = reinterpret_cast<uint4*>(glo + (((size_t)ch * NGRP + grp) << 9));
    hd[cw * 2 + 0] = hs[ch * 64 + cw * 2 + 0];
    hd[cw * 2 + 1] = hs[ch * 64 + cw * 2 + 1];
    ld[cw * 2 + 0] = ls[ch * 64 + cw * 2 + 0];
    ld[cw * 2 + 1] = ls[ch * 64 + cw * 2 + 1];
}

// ---------------------------------------------------------------------------
// Kernel 2: bf16 MFMA match, direct global->register, fragment time-sharing
// (fits the 128-reg granule -> 4 waves/SIMD), now in 2x2-WAVE BLOCKS for
// intra-CU L1 reuse: block = 256 thr = 4 waves (wr,wc) over a 128x128 tile;
// waves sharing wc read the SAME B tiles, sharing wr the same A tiles,
// guaranteed same-CU -> L1/MSHR merges halve the unique L1 fill per round
// (R18's single-wave blocks: each wave privately pulled 16KB/round through
// L1; L1-path ~24us/CU ~= MFMA floor -> memory-path-bound at MfmaUtil 31%).
// Per round: load bh,bl,ah up-front (12) -> pass hh -> pass hl -> load al
// into a (late 4) -> pass lh. No LDS, no barriers.
// Bijective chunked XCD swizzle (1792%8==0) for L2 locality.
// ---------------------------------------------------------------------------
__global__ __launch_bounds__(256, 4) void match_kernel(const ushort* __restrict__ ghi,
                                                       const ushort* __restrict__ glo,
                                                       float* __restrict__ pV1,
                                                       int* __restrict__ pI1,
                                                       float* __restrict__ pV2) {
    const int bid = blockIdx.x;                    // 1792 = 7 * 16 * 16
    const int swz = (bid & 7) * (1792 / 8) + (bid >> 3);   // bijective
    const int t   = swz >> 8;
    const int rbB = (swz >> 4) & 15;               // 128-row block panel
    const int cbB = swz & 15;                      // 128-col block panel
    const int tid = threadIdx.x;
    const int w   = tid >> 6;
    const int l   = tid & 63;
    const int rb  = rbB * 2 + (w >> 1);            // 64-row wave panel (0..31)
    const int cb  = cbB * 2 + (w & 1);             // 64-col wave panel (0..31)
    const size_t l8 = (size_t)(l << 3);            // lane's 8 shorts

    const int agrp = t * 128 + rb * 4;             // A frag groups (16 rows each)
    const int bgrp = (t + 1) * 128 + cb * 4;       // B frag groups
    const size_t RSTRIDE = (size_t)NGRP << 9;      // shorts per rd step

    const ushort* pAh = ghi + ((size_t)agrp << 9) + l8;
    const ushort* pAl = glo + ((size_t)agrp << 9) + l8;
    const ushort* pBh = ghi + ((size_t)bgrp << 9) + l8;
    const ushort* pBl = glo + ((size_t)bgrp << 9) + l8;

    float4v acc[4][4];
#pragma unroll
    for (int fa = 0; fa < 4; ++fa)
#pragma unroll
        for (int fb = 0; fb < 4; ++fb) acc[fa][fb] = (float4v){0.f, 0.f, 0.f, 0.f};

    short8v a[4], bh[4], bl[4];                    // a time-shares ah then al

#pragma unroll 1
    for (int rd = 0; rd < 8; ++rd) {
#pragma unroll
        for (int f = 0; f < 4; ++f)                // f*1024B: immediate offsets
            bh[f] = *reinterpret_cast<const short8v*>(pBh + (f << 9));
#pragma unroll
        for (int f = 0; f < 4; ++f)
            bl[f] = *reinterpret_cast<const short8v*>(pBl + (f << 9));
#pragma unroll
        for (int f = 0; f < 4; ++f)
            a[f]  = *reinterpret_cast<const short8v*>(pAh + (f << 9));
        // pass hh: ah x bh
#pragma unroll
        for (int fa = 0; fa < 4; ++fa)
#pragma unroll
            for (int fb = 0; fb < 4; ++fb)
                acc[fa][fb] = __builtin_amdgcn_mfma_f32_16x16x32_bf16(a[fa], bh[fb], acc[fa][fb], 0, 0, 0);
        // pass hl: ah x bl
#pragma unroll
        for (int fa = 0; fa < 4; ++fa)
#pragma unroll
            for (int fb = 0; fb < 4; ++fb)
                acc[fa][fb] = __builtin_amdgcn_mfma_f32_16x16x32_bf16(a[fa], bl[fb], acc[fa][fb], 0, 0, 0);
        // reuse a for al
#pragma unroll
        for (int f = 0; f < 4; ++f)
            a[f]  = *reinterpret_cast<const short8v*>(pAl + (f << 9));
        // pass lh: al x bh
#pragma unroll
        for (int fa = 0; fa < 4; ++fa)
#pragma unroll
            for (int fb = 0; fb < 4; ++fb)
                acc[fa][fb] = __builtin_amdgcn_mfma_f32_16x16x32_bf16(a[fa], bh[fb], acc[fa][fb], 0, 0, 0);
        pAh += RSTRIDE; pAl += RSTRIDE; pBh += RSTRIDE; pBl += RSTRIDE;
    }

    // ---- epilogue (in-wave): D row = fa*16+4*(l>>4)+r, col = cb*64+fb*16+(l&15)
#pragma unroll
    for (int fa = 0; fa < 4; ++fa) {
#pragma unroll
        for (int r = 0; r < 4; ++r) {
            float v1 = -3.0e38f, v2 = -3.0e38f; int i1 = 0;
#pragma unroll
            for (int fb = 0; fb < 4; ++fb) {
                float x  = acc[fa][fb][r];
                int  col = cb * 64 + fb * 16 + (l & 15);
                if (x > v1) { v2 = v1; v1 = x; i1 = col; }
                else        { v2 = fmaxf(v2, x); }
            }
#pragma unroll
            for (int m = 1; m <= 8; m <<= 1) {     // 16-lane butterfly
                float ov1 = __shfl_xor(v1, m);
                int   oi1 = __shfl_xor(i1, m);
                float ov2 = __shfl_xor(v2, m);
                bool take = (ov1 > v1) || (ov1 == v1 && oi1 < i1);
                float nv2 = take ? fmaxf(ov2, v1) : fmaxf(v2, ov1);
                v1 = take ? ov1 : v1;  i1 = take ? oi1 : i1;  v2 = nv2;
            }
            if ((l & 15) == 0) {
                int grow = t * NPTS + rb * 64 + fa * 16 + (l >> 4) * 4 + r;
                int idx  = grow * NPB + cb;
                pV1[idx] = v1; pI1[idx] = i1; pV2[idx] = v2;
            }
        }
    }
}

// ---------------------------------------------------------------------------
// Kernel 3: global top-2 margin per row; near-ties -> per-t worklist; safe
// rows commit approx best (value error <= 4.8e-5 << bf16-granular bar).
// ---------------------------------------------------------------------------
__global__ __launch_bounds__(256) void margin_kernel(const float* __restrict__ pV1,
                                                     const int* __restrict__ pI1,
                                                     const float* __restrict__ pV2,
                                                     unsigned long long* __restrict__ best,
                                                     int* __restrict__ wlT,
                                                     int* __restrict__ cntT) {
    int r = blockIdx.x * 256 + threadIdx.x;        // 0..14335
    int t = r >> 11;
    float v1 = -3.0e38f, v2 = -3.0e38f; int i1 = 0;
#pragma unroll
    for (int cbk = 0; cbk < NPB; ++cbk) {          // ascending -> first-occurrence
        int idx = r * NPB + cbk;
        float a1 = pV1[idx]; int ai = pI1[idx]; float a2 = pV2[idx];
        if (a1 > v1) { v2 = fmaxf(v1, a2); v1 = a1; i1 = ai; }
        else         { v2 = fmaxf(v2, a1); }
    }
    if (v1 - v2 < MARGIN_THR) {
        best[r] = 0ull;
        int slot = atomicAdd(&cntT[t], 1);
        wlT[t * NPTS + slot] = r & (NPTS - 1);     // row within frame
    } else {
        best[r] = packVI(v1, i1);
    }
}

// ---------------------------------------------------------------------------
// Kernel 4: exact fp32 rescore, loop-inverted + wave-parallel rows.
// Block = (t, 8-col slab); batch-stage <=24 flagged src rows + the dst slab
// in conflict-free [*][8][33] layouts; wave w handles rows w, w+4, ...
// independently; one atomicMax per row per slab (order-independent).
// ---------------------------------------------------------------------------
__global__ __launch_bounds__(256) void recheck_kernel(const float* __restrict__ nd,
                                                      const int* __restrict__ wlT,
                                                      const int* __restrict__ cntT,
                                                      unsigned long long* __restrict__ best) {
    __shared__ float dstS[RC_COLS][8][33];         // 8.25 KB  [col][kseg][k]
    __shared__ float srcS[RC_ROWS][8][33];         // 24.75 KB [row][kseg][k]
    const int t   = blockIdx.x >> 8;               // grid = 7 * 256
    const int cc  = blockIdx.x & 255;
    const int nr  = cntT[t];
    if (nr == 0) return;
    const int tid  = threadIdx.x;
    const int w    = tid >> 6;
    const int l    = tid & 63;
    const int col0 = cc * RC_COLS;

    {   // stage 8 dst cols: thread col=tid>>5, 2 float4 (8 floats) each
        const int col = tid >> 5;
        const int k8  = tid & 31;
        const float* dp = nd + ((size_t)((t + 1) * NPTS) + col0 + col) * DD;
#pragma unroll
        for (int j = 0; j < 2; ++j) {
            float4 v = reinterpret_cast<const float4*>(dp)[k8 * 2 + j];
            int k = (k8 * 2 + j) * 4;
            dstS[col][k >> 5][k & 31]       = v.x;
            dstS[col][(k+1) >> 5][(k+1)&31] = v.y;
            dstS[col][(k+2) >> 5][(k+2)&31] = v.z;
            dstS[col][(k+3) >> 5][(k+3)&31] = v.w;
        }
    }

#pragma unroll 1
    for (int base = 0; base < nr; base += RC_ROWS) {
        const int nb = min(RC_ROWS, nr - base);
        __syncthreads();                           // srcS free (dstS ready, 1st)
        for (int idx = tid; idx < nb * 64; idx += 256) {
            const int ri = idx >> 6, ln = idx & 63;
            const int row = wlT[t * NPTS + base + ri];
            float4 v = reinterpret_cast<const float4*>(
                nd + ((size_t)(t * NPTS) + row) * DD)[ln];
            int k = ln * 4;
            srcS[ri][k >> 5][k & 31]       = v.x;
            srcS[ri][(k+1) >> 5][(k+1)&31] = v.y;
            srcS[ri][(k+2) >> 5][(k+2)&31] = v.z;
            srcS[ri][(k+3) >> 5][(k+3)&31] = v.w;
        }
        __syncthreads();                           // batch staged

        const int colx = l & 7, ks = l >> 3;
#pragma unroll 1
        for (int ri = w; ri < nb; ri += 4) {       // waves independent
            const int row = wlT[t * NPTS + base + ri];
            const int r   = t * NPTS + row;
            float p = 0.f;
#pragma unroll
            for (int k = 0; k < 32; ++k)
                p = fmaf(srcS[ri][ks][k], dstS[colx][ks][k], p);
            p += __shfl_xor(p, 8); p += __shfl_xor(p, 16); p += __shfl_xor(p, 32);
            float bv = p; int bi = col0 + colx;
#pragma unroll
            for (int m = 1; m <= 4; m <<= 1) {     // top-1 across 8 cols
                float ov = __shfl_xor(bv, m);
                int   oi = __shfl_xor(bi, m);
                if (ov > bv || (ov == bv && oi < bi)) { bv = ov; bi = oi; }
            }
            if (l == 0) atomicMax(&best[r], packVI(bv, bi));
        }
    }
}

// ---------------------------------------------------------------------------
// Kernel 5: unpack best[], gather matched points, write outputs.
// ---------------------------------------------------------------------------
__global__ __launch_bounds__(256) void final_kernel(const unsigned long long* __restrict__ best,
                                                    const float* __restrict__ pts,
                                                    float* __restrict__ out) {
    int r = blockIdx.x * 256 + threadIdx.x;
    int t = r >> 11;
    unsigned long long p = best[r];
    int idx = NPTS - 1 - (int)(p & 0xFFFFFFFFull);
    unsigned int b = (unsigned int)(p >> 32);
    b = (b & 0x80000000u) ? (b & 0x7FFFFFFFu) : ~b;
    out[(size_t)T1 * NPTS * 2 + r] = __uint_as_float(b);
    const float* q = pts + ((size_t)((t + 1) * NPTS) + idx) * 2;
    out[(size_t)r * 2 + 0] = q[0];
    out[(size_t)r * 2 + 1] = q[1];
}

// ---------------------------------------------------------------------------
extern "C" void kernel_launch(void* const* d_in, const int* in_sizes, int n_in,
                              void* d_out, int out_size, void* d_ws, size_t ws_size,
                              hipStream_t stream) {
    const float* desc = (const float*)d_in[0];     // [8, 2048, 256] fp32
    const float* pts  = (const float*)d_in[1];     // [8, 2048, 2]   fp32
    float* ws = (float*)d_ws;
    float* nd  = ws + O_ND;
    ushort* ghi = (ushort*)(ws + O_HI);
    ushort* glo = (ushort*)(ws + O_LO);
    float* pV1 = ws + O_PV1;
    int*   pI1 = (int*)(ws + O_PI1);
    float* pV2 = ws + O_PV2;
    unsigned long long* best = (unsigned long long*)(ws + O_BEST);
    int* wlT  = (int*)(ws + O_WL);
    int* cntT = (int*)(ws + O_CNT);

    prep_kernel<<<T_ALL * NPTS / 16, 256, 0, stream>>>(desc, nd, ghi, glo, cntT);
    match_kernel<<<T1 * 16 * 16, 256, 0, stream>>>(ghi, glo, pV1, pI1, pV2);
    margin_kernel<<<(T1 * NPTS) / 256, 256, 0, stream>>>(pV1, pI1, pV2, best, wlT, cntT);
    recheck_kernel<<<T1 * 256, 256, 0, stream>>>(nd, wlT, cntT, best);
    final_kernel<<<(T1 * NPTS) / 256, 256, 0, stream>>>(best, pts, (float*)d_out);
}